// Round 4
// baseline (545.241 us; speedup 1.0000x reference)
//
#include <hip/hip_runtime.h>

// ---- problem constants ----
#define V_DIM   2048
#define Q_DIM   1024
#define NUM_HID 1024
#define BB 64
#define KK 12
#define NN 36
#define M_ROWS (BB*KK*NN)    // 27648 = 216 * 128, exact
#define BKROWS (BB*KK)       // 768   = 6 * 128,   exact

typedef unsigned short u16;
typedef __bf16 bf16x8  __attribute__((ext_vector_type(8)));
typedef u16    ushort8 __attribute__((ext_vector_type(8)));
typedef float  floatx4 __attribute__((ext_vector_type(4)));

// fp32 -> bf16 RNE, 2-at-a-time (guide T12: no builtin on gfx950, inline asm verified)
__device__ __forceinline__ unsigned cvtpk(float lo, float hi) {
    unsigned r;
    asm("v_cvt_pk_bf16_f32 %0, %1, %2" : "=v"(r) : "v"(lo), "v"(hi));
    return r;
}

// async global->LDS, 16B per lane. LDS dest = wave-uniform base + lane*16 (HW).
__device__ __forceinline__ void gload16(const u16* g, u16* l) {
    __builtin_amdgcn_global_load_lds((const __attribute__((address_space(1))) void*)g,
                                     (__attribute__((address_space(3))) void*)l, 16, 0, 0);
}

// ---- W1 fp32 (1024 x 3072) -> bf16 W1v (1024x2048) + W1q (1024x1024),
//      fused ||W1||^2 atomic reduction; LAST block (ticket) also computes
//      ||W2||^2 and writes final scales wsf[2]=g1/||W1||, wsf[3]=g2/||W2||. ----
__global__ void convert_w1_kernel(const float* __restrict__ W1,
                                  u16* __restrict__ W1v, u16* __restrict__ W1q,
                                  const float* __restrict__ W2,
                                  const float* __restrict__ g1,
                                  const float* __restrict__ g2,
                                  float* __restrict__ wsf)
{
    int s = blockIdx.x * 256 + threadIdx.x;          // grid 1536*256 = 393216 exact
    int h = s / 384, g = s % 384;
    const float4* p = (const float4*)(W1 + (size_t)h * (V_DIM + Q_DIM) + g * 8);
    float4 a = p[0], b = p[1];
    float ss = a.x*a.x + a.y*a.y + a.z*a.z + a.w*a.w
             + b.x*b.x + b.y*b.y + b.z*b.z + b.w*b.w;
    unsigned d0 = cvtpk(a.x, a.y), d1 = cvtpk(a.z, a.w);
    unsigned d2 = cvtpk(b.x, b.y), d3 = cvtpk(b.z, b.w);
    uint4 o = make_uint4(d0, d1, d2, d3);
    if (g < 256) *(uint4*)(W1v + (size_t)h * V_DIM + g * 8) = o;
    else         *(uint4*)(W1q + (size_t)h * Q_DIM + (g - 256) * 8) = o;
    #pragma unroll
    for (int off = 32; off > 0; off >>= 1) ss += __shfl_down(ss, off);
    __shared__ float red[4];
    __shared__ bool  last;
    if ((threadIdx.x & 63) == 0) red[threadIdx.x >> 6] = ss;
    __syncthreads();
    if (threadIdx.x == 0) {
        atomicAdd(wsf, red[0] + red[1] + red[2] + red[3]);
        __threadfence();
        unsigned t = atomicAdd((unsigned*)(wsf + 1), 1u);
        last = (t == gridDim.x - 1);
    }
    __syncthreads();
    if (last) {
        // this block runs after all ||W1||^2 adds have completed
        float4 w = ((const float4*)W2)[threadIdx.x];     // 256 threads x 4 = 1024
        float s2 = w.x*w.x + w.y*w.y + w.z*w.z + w.w*w.w;
        #pragma unroll
        for (int off = 32; off > 0; off >>= 1) s2 += __shfl_down(s2, off);
        __shared__ float red2[4];
        if ((threadIdx.x & 63) == 0) red2[threadIdx.x >> 6] = s2;
        __syncthreads();
        if (threadIdx.x == 0) {
            float w2ss = red2[0] + red2[1] + red2[2] + red2[3];
            float w1ss = atomicAdd(wsf, 0.0f);           // device-scope atomic read
            wsf[2] = g1[0] / sqrtf(w1ss);
            wsf[3] = g2[0] / sqrtf(w2ss);
        }
    }
}

// ---- MFMA GEMM: C(M x 1024) = A(M x GK, fp32, cvt_pk on the fly) * B(GK x 1024)
//      B bf16 [1024][GK] row-major, staged via global_load_lds, XOR-swizzled source
//      (measured 0 conflicts). A fp32 reg-staged -> cvt_pk -> ds_write_b128 into the
//      SAME XOR-swizzled [128][64] layout (round-1-verified read path; fixes the
//      7.08M-conflict 72-pad layout of round 3).
// MAIN=true : fused epilogue  partial[row][tx*2+wn] = sum_cols relu(s1*(acc+hq)+b1)*W2
// MAIN=false: writes raw acc to outp[row*1024 + col]   (the hq pass)
// Tiles: BM=BN=128, BK=64. 256 threads = 4 waves (2x2), each wave 64x64 via 4x4 MFMA.
// XCD swizzle: n-minor so the 8 same-XCD consecutive blocks share the fp32 A panel.
template<int GK, bool MAIN>
__global__ __launch_bounds__(256, 2)
void gemm_kernel(const float* __restrict__ Asrc,
                 const u16*   __restrict__ Bsrc,
                 float*       __restrict__ outp,
                 const float* __restrict__ hq,
                 const float* __restrict__ b1,
                 const float* __restrict__ W2,
                 const float* __restrict__ scl)
{
    __shared__ u16 As[128 * 64];
    __shared__ u16 Bs[128 * 64];

    const int tid  = threadIdx.x;
    const int lane = tid & 63;
    const int wv   = tid >> 6;
    const int wm   = wv & 1;          // wave row (0..1)
    const int wn   = wv >> 1;         // wave col (0..1)
    const int quad = lane >> 4;
    const int l15  = lane & 15;

    // bijective XCD swizzle; nwg % 8 == 0 for both grids
    const int bid  = blockIdx.y * 8 + blockIdx.x;
    const int nwg  = gridDim.x * gridDim.y;
    const int tile = (bid & 7) * (nwg >> 3) + (bid >> 3);
    const int tx   = tile & 7;
    const int ty   = tile >> 3;
    const int m0   = ty * 128;
    const int n0   = tx * 128;

    floatx4 acc[4][4];
    #pragma unroll
    for (int i = 0; i < 4; i++)
        #pragma unroll
        for (int j = 0; j < 4; j++)
            acc[i][j] = (floatx4){0.f, 0.f, 0.f, 0.f};

    for (int kt = 0; kt < GK / 64; ++kt) {
        const int k0 = kt * 64;
        __syncthreads();
        // ---- stage A: fp32 -> bf16 via cvt_pk, XOR-swizzled [128][64] LDS ----
        #pragma unroll
        for (int it = 0; it < 4; ++it) {
            int s = tid + 256 * it;
            int r = s >> 3, g = s & 7;
            const float4* gp = (const float4*)(Asrc + (size_t)(m0 + r) * GK + k0 + g * 8);
            float4 f0 = gp[0];
            float4 f1 = gp[1];
            unsigned d0 = cvtpk(f0.x, f0.y), d1 = cvtpk(f0.z, f0.w);
            unsigned d2 = cvtpk(f1.x, f1.y), d3 = cvtpk(f1.z, f1.w);
            *(uint4*)(&As[r * 64 + ((g ^ (r & 7)) * 8)]) = make_uint4(d0, d1, d2, d3);
        }
        // ---- stage B: bf16 via global_load_lds, XOR-swizzled source ----
        #pragma unroll
        for (int it = 0; it < 4; ++it) {
            int sbase = it * 256 + wv * 64;            // wave-uniform slot base
            int s = sbase + lane;
            int c = s >> 3, g = s & 7;
            int gs = g ^ (c & 7);
            gload16(Bsrc + (size_t)(n0 + c) * GK + k0 + gs * 8, &Bs[sbase * 8]);
        }
        __syncthreads();
        // ---- compute: 2 k-steps of 32 ----
        #pragma unroll
        for (int ks = 0; ks < 2; ++ks) {
            bf16x8 af[4], bfr[4];
            #pragma unroll
            for (int i = 0; i < 4; i++) {
                int rA = wm * 64 + i * 16 + l15;
                int offA = (ks * 32 + quad * 8) ^ ((rA & 7) << 3);
                af[i] = *(const bf16x8*)(&As[rA * 64 + offA]);
            }
            #pragma unroll
            for (int j = 0; j < 4; j++) {
                int c = wn * 64 + j * 16 + l15;
                int offB = (ks * 32 + quad * 8) ^ ((c & 7) << 3);
                bfr[j] = *(const bf16x8*)(&Bs[c * 64 + offB]);
            }
            #pragma unroll
            for (int i = 0; i < 4; i++)
                #pragma unroll
                for (int j = 0; j < 4; j++)
                    acc[i][j] = __builtin_amdgcn_mfma_f32_16x16x32_bf16(af[i], bfr[j], acc[i][j], 0, 0, 0);
        }
    }

    if constexpr (MAIN) {
        const float s1 = scl[2];
        int   cg[4];
        float w2v[4], b1v[4];
        #pragma unroll
        for (int j = 0; j < 4; j++) {
            cg[j]  = n0 + wn * 64 + j * 16 + l15;
            w2v[j] = W2[cg[j]];
            b1v[j] = b1[cg[j]];
        }
        #pragma unroll
        for (int i = 0; i < 4; i++) {
            #pragma unroll
            for (int r = 0; r < 4; r++) {
                const int mg = m0 + wm * 64 + i * 16 + quad * 4 + r;
                const int bk = mg / NN;
                float p = 0.f;
                #pragma unroll
                for (int j = 0; j < 4; j++) {
                    float pre = s1 * (acc[i][j][r] + hq[(size_t)bk * NUM_HID + cg[j]]) + b1v[j];
                    p += fmaxf(pre, 0.f) * w2v[j];
                }
                // reduce over the 16 column-lanes of this quad (row is quad-local)
                p += __shfl_xor(p, 1);
                p += __shfl_xor(p, 2);
                p += __shfl_xor(p, 4);
                p += __shfl_xor(p, 8);
                if (l15 == 0)
                    outp[(size_t)mg * 16 + tx * 2 + wn] = p;
            }
        }
    } else {
        #pragma unroll
        for (int i = 0; i < 4; i++)
            #pragma unroll
            for (int r = 0; r < 4; r++) {
                const int mg = m0 + wm * 64 + i * 16 + quad * 4 + r;
                #pragma unroll
                for (int j = 0; j < 4; j++) {
                    const int c = n0 + wn * 64 + j * 16 + l15;
                    outp[(size_t)mg * NUM_HID + c] = acc[i][j][r];
                }
            }
    }
}

// ---- softmax over K=12 per (b,n); logits = s2*sum(partials) + b2 ----
__global__ void softmax_kernel(const float* __restrict__ part,
                               const float* __restrict__ scl,
                               const float* __restrict__ b2,
                               float* __restrict__ out)
{
    int t = blockIdx.x * 64 + threadIdx.x;   // grid 36*64 = 2304 exact
    int b = t / NN, n = t % NN;
    float s2 = scl[3], bias = b2[0];
    float lg[KK];
    float mx = -1e30f;
    #pragma unroll
    for (int k = 0; k < KK; k++) {
        int m = (b * KK + k) * NN + n;
        const float4* pp = (const float4*)(part + (size_t)m * 16);
        float4 a0 = pp[0], a1 = pp[1], a2 = pp[2], a3 = pp[3];
        float s = (a0.x + a0.y + a0.z + a0.w) + (a1.x + a1.y + a1.z + a1.w)
                + (a2.x + a2.y + a2.z + a2.w) + (a3.x + a3.y + a3.z + a3.w);
        lg[k] = s2 * s + bias;
        mx = fmaxf(mx, lg[k]);
    }
    float den = 0.f;
    #pragma unroll
    for (int k = 0; k < KK; k++) { lg[k] = expf(lg[k] - mx); den += lg[k]; }
    float inv = 1.0f / den;
    #pragma unroll
    for (int k = 0; k < KK; k++) out[(size_t)((b * KK + k) * NN + n)] = lg[k] * inv;
}

extern "C" void kernel_launch(void* const* d_in, const int* in_sizes, int n_in,
                              void* d_out, int out_size, void* d_ws, size_t ws_size,
                              hipStream_t stream)
{
    (void)in_sizes; (void)n_in; (void)out_size; (void)ws_size;
    const float* v  = (const float*)d_in[0];
    const float* q  = (const float*)d_in[1];
    const float* W1 = (const float*)d_in[2];
    const float* g1 = (const float*)d_in[3];
    const float* b1 = (const float*)d_in[4];
    const float* W2 = (const float*)d_in[5];
    const float* g2 = (const float*)d_in[6];
    const float* b2 = (const float*)d_in[7];
    float* out = (float*)d_out;

    // ws layout (bytes):
    //   0      : 4 floats  [w1_sumsq, ticket, s1, s2]
    //   16     : hq  fp32 [768][1024]            (3,145,728 B)
    //   3145744: W1v bf16 [1024][2048]           (4,194,304 B)
    //   7340048: W1q bf16 [1024][1024]           (2,097,152 B)
    //   9437200: part fp32 [27648][16]           (1,769,472 B)  -> total ~11.2 MB
    char*  ws   = (char*)d_ws;
    float* wsf  = (float*)ws;
    float* hq   = (float*)(ws + 16);
    u16*   W1v  = (u16*)  (ws + 16 + 3145728);
    u16*   W1q  = (u16*)  (ws + 16 + 3145728 + 4194304);
    float* part = (float*)(ws + 16 + 3145728 + 4194304 + 2097152);

    hipMemsetAsync(d_ws, 0, 16, stream);
    // convert W1 (+ fused ||W1||^2, ||W2||^2, final scales via last-block ticket)
    convert_w1_kernel<<<1536, 256, 0, stream>>>(W1, W1v, W1q, W2, g1, g2, wsf);
    // hq = q @ W1q^T (raw, unscaled):  M=768 -> grid (8 ntiles, 6 mtiles)
    gemm_kernel<Q_DIM, false><<<dim3(8, 6), 256, 0, stream>>>(
        q, W1q, hq, nullptr, nullptr, nullptr, wsf);
    // main: per-row partial logits, fp32 A converted in-kernel
    gemm_kernel<V_DIM, true><<<dim3(8, 216), 256, 0, stream>>>(
        v, W1v, part, hq, b1, W2, wsf);
    softmax_kernel<<<36, 64, 0, stream>>>(part, wsf, b2, out);
}